// Round 8
// baseline (310.609 us; speedup 1.0000x reference)
//
#include <hip/hip_runtime.h>
#include <math.h>

// Folded model (exact algebra, per-token):
//   h      = relu(x @ G1 + b11)                      [400 MACs]
//   g      = relu(h @ P1 + x @ P2 + f2)              [800 MACs]
//   logits = g @ M2 + h @ Q1 + x @ Q2 + f3           [180 MACs]
//   out    = softmax(logits)
// Logits weights stored TRANSPOSED and c-padded to 4 (M2T/Q1T/Q2T: [20][4]).

// d_ws layout (float offsets), 16B-aligned rows
#define OFF_G1   0      // [20][20] k-major
#define OFF_P1   400    // [20][20] m'-major
#define OFF_P2   800    // [20][20] k-major
#define OFF_M2T  1200   // [20][4]  M2T[m][c] = sum_p Wc[c][p]*W2_1[p][m], c3=0
#define OFF_Q1T  1280   // [20][4]  Q1T[k][c]
#define OFF_Q2T  1360   // [20][4]  Q2T[k][c]
#define OFF_B11  1440   // [20]
#define OFF_F2   1460   // [20]
#define OFF_F3   1480   // [3] + pad
#define NWTOT    1484

__global__ void prep_kernel(const float* __restrict__ Wv, const float* __restrict__ Wres,
                            const float* __restrict__ W1, const float* __restrict__ b1,
                            const float* __restrict__ W2, const float* __restrict__ b2,
                            const float* __restrict__ W3, const float* __restrict__ b3,
                            const float* __restrict__ Wc, const float* __restrict__ bc,
                            float* __restrict__ W) {
    __shared__ float G2[400];   // [i][m]
    __shared__ float M3[60];    // [i][c]
    __shared__ float e1[20];
    const int tid = threadIdx.x;
    for (int idx = tid; idx < 480; idx += 256) {
        if (idx < 400) {
            const int i = idx / 20, m = idx % 20;
            float s = 0.f;
            for (int j = 0; j < 20; ++j)
                s = fmaf(Wv[400 + j*20 + i] + Wres[400 + i*20 + j], W1[400 + m*20 + j], s);
            G2[idx] = s;
        } else if (idx < 460) {
            const int r = idx - 400, i = r / 3, c = r % 3;
            float s = 0.f;
            for (int p = 0; p < 20; ++p)
                s = fmaf(Wc[c*20 + p], W3[400 + p*20 + i], s);
            M3[r] = s;
        } else {
            const int j = idx - 460;
            e1[j] = b2[j] + b3[j];
        }
    }
    __syncthreads();
    for (int idx = tid; idx < NWTOT; idx += 256) {
        float s = 0.f;
        if (idx < 400) {                       // G1[k][m]
            const int k = idx / 20, m = idx % 20;
            for (int j = 0; j < 20; ++j)
                s = fmaf(Wv[j*20 + k] + Wres[k*20 + j], W1[m*20 + j], s);
        } else if (idx < 800) {                // P1[m'][m]
            const int r = idx - 400, mp = r / 20, m = r % 20;
            for (int i = 0; i < 20; ++i)
                s = fmaf(W2[i*20 + mp], G2[i*20 + m], s);
        } else if (idx < 1200) {               // P2[k][m]
            const int r = idx - 800, k = r / 20, m = r % 20;
            for (int i = 0; i < 20; ++i)
                s = fmaf(W3[i*20 + k], G2[i*20 + m], s);
        } else if (idx < 1280) {               // M2T[m][c]
            const int r = idx - 1200, m = r / 4, c = r % 4;
            if (c < 3)
                for (int p = 0; p < 20; ++p)
                    s = fmaf(Wc[c*20 + p], W2[400 + p*20 + m], s);
        } else if (idx < 1360) {               // Q1T[k][c]
            const int r = idx - 1280, k = r / 4, c = r % 4;
            if (c < 3)
                for (int i = 0; i < 20; ++i)
                    s = fmaf(W2[i*20 + k], M3[i*3 + c], s);
        } else if (idx < 1440) {               // Q2T[k][c]
            const int r = idx - 1360, k = r / 4, c = r % 4;
            if (c < 3)
                for (int i = 0; i < 20; ++i)
                    s = fmaf(W3[i*20 + k], M3[i*3 + c], s);
        } else if (idx < 1460) {               // b11
            s = b1[idx - 1440];
        } else if (idx < 1480) {               // f2
            const int m = idx - 1460;
            s = b1[20 + m];
            for (int i = 0; i < 20; ++i)
                s = fmaf(e1[i], G2[i*20 + m], s);
        } else {                               // f3 (+1 pad = 0)
            const int c = idx - 1480;
            if (c < 3) {
                s = bc[c];
                for (int p = 0; p < 20; ++p)
                    s = fmaf(Wc[c*20 + p], b2[20 + p] + b3[20 + p], s);
                for (int i = 0; i < 20; ++i)
                    s = fmaf(e1[i], M3[i*3 + c], s);
            }
        }
        W[idx] = s;
    }
}

// T=1, ALL weights via VMEM/L1 vector loads + packed fp32 FMA.
// Evidence (8 runs): the ~130k-cyc/CU wall is the uniform weight-delivery
// pipe — LDS broadcast (r0: 356 v4 x 12cyc x 32 waves = 137k, exact) and
// SGPR-batched s_load (r1/r2/r4/r7: ~5 loads in flight under the SGPR
// budget -> serialized K$ rounds) both saturate there; VALU halving (r7 pk)
// left duration unchanged. The untried pipe: weights (5.9 KB, L1-resident)
// as VECTOR global loads with uniform address — vmcnt-counted, deeply
// pipelined (tens in flight), ~1 L1 hit/cyc: 371 v4 x 64 waves = 24k
// cyc/CU, 5x under the wall. hipcc scalarizes uniform const loads back to
// s_load, so the base pointer is made opaque-divergent via an inline-asm
// v_mov zero. Two bases keep the 13-bit signed global-load offsets <4096 B.
// T=1 + chunk-x + all-pk: ~840 VALU instr/thread -> 27k cyc/SIMD floor;
// live set ~90-110 VGPRs under the (256,2) 128-grant (r3 evidence).
typedef float f2  __attribute__((ext_vector_type(2)));
typedef float v4f __attribute__((ext_vector_type(4)));

__device__ __forceinline__ v4f ldw(const float* p) {
    return *reinterpret_cast<const v4f*>(p);
}

__global__ __launch_bounds__(256, 2) void fwd_kernel(const float* __restrict__ X,
                                                     const float* __restrict__ Wg,
                                                     float* __restrict__ out, int ntok) {
    // opaque per-lane zero: defeats uniform-load scalarization, forcing
    // global_load_dwordx4 (L1 vector path) for all weight reads.
    int z;
    asm volatile("v_mov_b32 %0, 0" : "=v"(z));
    const float* Wd  = Wg + z;      // base for G1 (0..1600B) and P1 (1600..3184B)
    const float* Wd2 = Wd + 800;    // base for P2/M2T/Q1T/Q2T/biases (rel < 2736B)

    const int tid = blockIdx.x * blockDim.x + threadIdx.x;
    if (tid >= ntok) return;
    const float4* xp = reinterpret_cast<const float4*>(X + (size_t)tid * 20);

    f2 h2[10], g2[10], la2[2];

    // init: h = b11, g = f2, la = f3  (rel offsets to Wd2: 640 / 660 / 680)
    #pragma unroll
    for (int q = 0; q < 5; ++q) {
        const v4f b = ldw(Wd2 + 640 + 4*q);
        const v4f f = ldw(Wd2 + 660 + 4*q);
        f2 blo = {b.x, b.y}, bhi = {b.z, b.w};
        f2 flo = {f.x, f.y}, fhi = {f.z, f.w};
        h2[2*q+0] = blo; h2[2*q+1] = bhi;
        g2[2*q+0] = flo; g2[2*q+1] = fhi;
    }
    {
        const v4f f3 = ldw(Wd2 + 680);          // {f3_0, f3_1, f3_2, 0}
        f2 lo = {f3.x, f3.y}, hi = {f3.z, f3.w};
        la2[0] = lo; la2[1] = hi;
    }

    // ---- loop1: h += x@G1 ; g += x@P2 ; la += x@Q2T  (x chunk-wise) ----
    #pragma unroll
    for (int q = 0; q < 5; ++q) {
        const float4 xv = xp[q];
        float xc[4];
        xc[0] = xv.x; xc[1] = xv.y; xc[2] = xv.z; xc[3] = xv.w;
        #pragma unroll
        for (int d = 0; d < 4; ++d) {
            const int k = 4*q + d;
            const float xk = xc[d];
            const f2 xkp = {xk, xk};
            {
                const v4f w = ldw(Wd2 + 560 + 4*k);      // Q2T[k]
                const f2 wlo = {w.x, w.y}, whi = {w.z, w.w};
                la2[0] = __builtin_elementwise_fma(xkp, wlo, la2[0]);
                la2[1] = __builtin_elementwise_fma(xkp, whi, la2[1]);
            }
            #pragma unroll
            for (int r = 0; r < 5; ++r) {
                const v4f w = ldw(Wd + k*20 + 4*r);      // G1[k]
                const f2 wlo = {w.x, w.y}, whi = {w.z, w.w};
                h2[2*r+0] = __builtin_elementwise_fma(xkp, wlo, h2[2*r+0]);
                h2[2*r+1] = __builtin_elementwise_fma(xkp, whi, h2[2*r+1]);
            }
            #pragma unroll
            for (int r = 0; r < 5; ++r) {
                const v4f w = ldw(Wd2 + k*20 + 4*r);     // P2[k]
                const f2 wlo = {w.x, w.y}, whi = {w.z, w.w};
                g2[2*r+0] = __builtin_elementwise_fma(xkp, wlo, g2[2*r+0]);
                g2[2*r+1] = __builtin_elementwise_fma(xkp, whi, g2[2*r+1]);
            }
        }
    }

    // relu h (packed)
    {
        const f2 z2 = {0.f, 0.f};
        #pragma unroll
        for (int p = 0; p < 10; ++p) h2[p] = __builtin_elementwise_max(h2[p], z2);
    }

    // ---- loop2: g += h@P1 ; la += h@Q1T ----
    #pragma unroll
    for (int k = 0; k < 20; ++k) {
        const float hk = (k & 1) ? h2[k>>1].y : h2[k>>1].x;
        const f2 hkp = {hk, hk};
        {
            const v4f w = ldw(Wd2 + 480 + 4*k);          // Q1T[k]
            const f2 wlo = {w.x, w.y}, whi = {w.z, w.w};
            la2[0] = __builtin_elementwise_fma(hkp, wlo, la2[0]);
            la2[1] = __builtin_elementwise_fma(hkp, whi, la2[1]);
        }
        #pragma unroll
        for (int r = 0; r < 5; ++r) {
            const v4f w = ldw(Wd + 400 + k*20 + 4*r);    // P1[k]
            const f2 wlo = {w.x, w.y}, whi = {w.z, w.w};
            g2[2*r+0] = __builtin_elementwise_fma(hkp, wlo, g2[2*r+0]);
            g2[2*r+1] = __builtin_elementwise_fma(hkp, whi, g2[2*r+1]);
        }
    }

    // relu g (packed)
    {
        const f2 z2 = {0.f, 0.f};
        #pragma unroll
        for (int p = 0; p < 10; ++p) g2[p] = __builtin_elementwise_max(g2[p], z2);
    }

    // ---- loop3: la += g@M2T (pad col = 0) ----
    #pragma unroll
    for (int k = 0; k < 20; ++k) {
        const float gk = (k & 1) ? g2[k>>1].y : g2[k>>1].x;
        const f2 gkp = {gk, gk};
        const v4f w = ldw(Wd2 + 400 + 4*k);              // M2T[k]
        const f2 wlo = {w.x, w.y}, whi = {w.z, w.w};
        la2[0] = __builtin_elementwise_fma(gkp, wlo, la2[0]);
        la2[1] = __builtin_elementwise_fma(gkp, whi, la2[1]);
    }

    // softmax + store (3 floats per token)
    const float l0 = la2[0].x, l1 = la2[0].y, l2 = la2[1].x;
    const float m = fmaxf(fmaxf(l0, l1), l2);
    const float e0 = __expf(l0 - m), e1 = __expf(l1 - m), e2 = __expf(l2 - m);
    const float r = 1.f / (e0 + e1 + e2);
    float* o = out + (size_t)tid * 3;
    o[0] = e0 * r;
    o[1] = e1 * r;
    o[2] = e2 * r;
}

extern "C" void kernel_launch(void* const* d_in, const int* in_sizes, int n_in,
                              void* d_out, int out_size, void* d_ws, size_t ws_size,
                              hipStream_t stream) {
    const float* X    = (const float*)d_in[0];
    // d_in[1]=Wq, d_in[2]=Wk: dead (softmax over singleton axis == 1)
    const float* Wv   = (const float*)d_in[3];
    const float* Wres = (const float*)d_in[4];
    const float* W1   = (const float*)d_in[5];
    const float* b1   = (const float*)d_in[6];
    const float* W2   = (const float*)d_in[7];
    const float* b2   = (const float*)d_in[8];
    const float* W3   = (const float*)d_in[9];
    const float* b3   = (const float*)d_in[10];
    const float* Wc   = (const float*)d_in[11];
    const float* bc   = (const float*)d_in[12];
    float* out = (float*)d_out;
    float* W   = (float*)d_ws;

    const int S = in_sizes[0] / 20;

    prep_kernel<<<1, 256, 0, stream>>>(Wv, Wres, W1, b1, W2, b2, W3, b3, Wc, bc, W);

    const int block = 256;
    const int grid = (S + block - 1) / block;
    fwd_kernel<<<grid, block, 0, stream>>>(X, W, out, S);
}

// Round 9
// 194.039 us; speedup vs baseline: 1.6008x; 1.6008x over previous
//
#include <hip/hip_runtime.h>
#include <math.h>

// Folded model (exact algebra, per-token):
//   h      = relu(x @ G1 + b11)                      [400 MACs]
//   g      = relu(h @ P1 + x @ P2 + f2)              [800 MACs]
//   logits = g @ M2 + h @ Q1 + x @ Q2 + f3           [180 MACs]
//   out    = softmax(logits)
// Logits weights stored TRANSPOSED and c-padded to 4 (M2T/Q1T/Q2T: [20][4]).

// d_ws layout (float offsets), 16B-aligned rows
#define OFF_G1   0      // [20][20] k-major
#define OFF_P1   400    // [20][20] m'-major
#define OFF_P2   800    // [20][20] k-major
#define OFF_M2T  1200   // [20][4]  M2T[m][c] = sum_p Wc[c][p]*W2_1[p][m], c3=0
#define OFF_Q1T  1280   // [20][4]  Q1T[k][c]
#define OFF_Q2T  1360   // [20][4]  Q2T[k][c]
#define OFF_B11  1440   // [20]
#define OFF_F2   1460   // [20]
#define OFF_F3   1480   // [3] + pad
#define NWTOT    1484

__global__ void prep_kernel(const float* __restrict__ Wv, const float* __restrict__ Wres,
                            const float* __restrict__ W1, const float* __restrict__ b1,
                            const float* __restrict__ W2, const float* __restrict__ b2,
                            const float* __restrict__ W3, const float* __restrict__ b3,
                            const float* __restrict__ Wc, const float* __restrict__ bc,
                            float* __restrict__ W) {
    __shared__ float G2[400];   // [i][m]
    __shared__ float M3[60];    // [i][c]
    __shared__ float e1[20];
    const int tid = threadIdx.x;
    for (int idx = tid; idx < 480; idx += 256) {
        if (idx < 400) {
            const int i = idx / 20, m = idx % 20;
            float s = 0.f;
            for (int j = 0; j < 20; ++j)
                s = fmaf(Wv[400 + j*20 + i] + Wres[400 + i*20 + j], W1[400 + m*20 + j], s);
            G2[idx] = s;
        } else if (idx < 460) {
            const int r = idx - 400, i = r / 3, c = r % 3;
            float s = 0.f;
            for (int p = 0; p < 20; ++p)
                s = fmaf(Wc[c*20 + p], W3[400 + p*20 + i], s);
            M3[r] = s;
        } else {
            const int j = idx - 460;
            e1[j] = b2[j] + b3[j];
        }
    }
    __syncthreads();
    for (int idx = tid; idx < NWTOT; idx += 256) {
        float s = 0.f;
        if (idx < 400) {                       // G1[k][m]
            const int k = idx / 20, m = idx % 20;
            for (int j = 0; j < 20; ++j)
                s = fmaf(Wv[j*20 + k] + Wres[k*20 + j], W1[m*20 + j], s);
        } else if (idx < 800) {                // P1[m'][m]
            const int r = idx - 400, mp = r / 20, m = r % 20;
            for (int i = 0; i < 20; ++i)
                s = fmaf(W2[i*20 + mp], G2[i*20 + m], s);
        } else if (idx < 1200) {               // P2[k][m]
            const int r = idx - 800, k = r / 20, m = r % 20;
            for (int i = 0; i < 20; ++i)
                s = fmaf(W3[i*20 + k], G2[i*20 + m], s);
        } else if (idx < 1280) {               // M2T[m][c]
            const int r = idx - 1200, m = r / 4, c = r % 4;
            if (c < 3)
                for (int p = 0; p < 20; ++p)
                    s = fmaf(Wc[c*20 + p], W2[400 + p*20 + m], s);
        } else if (idx < 1360) {               // Q1T[k][c]
            const int r = idx - 1280, k = r / 4, c = r % 4;
            if (c < 3)
                for (int i = 0; i < 20; ++i)
                    s = fmaf(W2[i*20 + k], M3[i*3 + c], s);
        } else if (idx < 1440) {               // Q2T[k][c]
            const int r = idx - 1360, k = r / 4, c = r % 4;
            if (c < 3)
                for (int i = 0; i < 20; ++i)
                    s = fmaf(W3[i*20 + k], M3[i*3 + c], s);
        } else if (idx < 1460) {               // b11
            s = b1[idx - 1440];
        } else if (idx < 1480) {               // f2
            const int m = idx - 1460;
            s = b1[20 + m];
            for (int i = 0; i < 20; ++i)
                s = fmaf(e1[i], G2[i*20 + m], s);
        } else {                               // f3 (+1 pad = 0)
            const int c = idx - 1480;
            if (c < 3) {
                s = bc[c];
                for (int p = 0; p < 20; ++p)
                    s = fmaf(Wc[c*20 + p], b2[20 + p] + b3[20 + p], s);
                for (int i = 0; i < 20; ++i)
                    s = fmaf(e1[i], M3[i*3 + c], s);
            }
        }
        W[idx] = s;
    }
}

// T=4, all-LDS weights, pk-fma, __launch_bounds__(256, 1).
// 9-round model: duration = weight-requests/wave x cost x waves/CU; waves/CU
// = 4096/(64T). Every T<=2 variant = ~130k cyc wall (LDS: 371 v4 x 12cyc x
// 32 waves = 137k exact). Only T divides it. T=4 was blocked by registers:
// arch-VGPR budget = 256/min_waves_per_EU ((256,2)->128 r3-spill,
// (256,3)->85, (256,6)->42). min_waves=1 -> budget 256; T=4 peak live
// ~230 (h 80 + g 80 + la 16 + x 2chunks 32 + weights ~24) fits. Loop1
// rolled with explicit next-chunk prefetch so x can't be bulk-hoisted
// (80 VGPRs) past the budget; loops 2/3 fully unrolled. All weights via
// LDS broadcast (single pipe, no lgkmcnt mixing with s_load).
// Target: 371 x 12 x 16 waves/CU = 71k cyc = ~30us.
typedef float f2  __attribute__((ext_vector_type(2)));
typedef float v4f __attribute__((ext_vector_type(4)));

__global__ __launch_bounds__(256, 1) void fwd_kernel(const float* __restrict__ X,
                                                     const float* __restrict__ Wg,
                                                     float* __restrict__ out, int nquad) {
    __shared__ float Ws[NWTOT];
    for (int i = threadIdx.x; i < NWTOT; i += 256) Ws[i] = Wg[i];
    __syncthreads();
    const v4f* L4 = reinterpret_cast<const v4f*>(Ws);

    const int tid = blockIdx.x * blockDim.x + threadIdx.x;
    if (tid >= nquad) return;
    const float4* xp = reinterpret_cast<const float4*>(X + (size_t)tid * 80);

    f2 h2[4][10], g2[4][10], la2[4][2];

    // init: h = b11, g = f2, la = f3 (all from LDS)
    #pragma unroll
    for (int q = 0; q < 5; ++q) {
        const v4f b = L4[360 + q];
        const v4f f = L4[365 + q];
        #pragma unroll
        for (int t = 0; t < 4; ++t) {
            f2 blo = {b.x, b.y}, bhi = {b.z, b.w};
            f2 flo = {f.x, f.y}, fhi = {f.z, f.w};
            h2[t][2*q+0] = blo; h2[t][2*q+1] = bhi;
            g2[t][2*q+0] = flo; g2[t][2*q+1] = fhi;
        }
    }
    {
        const v4f f3 = L4[370];                // {f3_0, f3_1, f3_2, 0}
        #pragma unroll
        for (int t = 0; t < 4; ++t) {
            f2 lo = {f3.x, f3.y}, hi = {f3.z, f3.w};
            la2[t][0] = lo; la2[t][1] = hi;
        }
    }

    // ---- loop1 (rolled over q, prefetch q+1): per k: h += x@G1 ;
    //      g += x@P2 ; la += x@Q2T.  x lives as 2 chunks (32 VGPR). ----
    float4 xc0 = xp[0], xc1 = xp[5], xc2 = xp[10], xc3 = xp[15];
    #pragma unroll 1
    for (int q = 0; q < 5; ++q) {
        const int qn = (q < 4) ? (q + 1) : 4;
        const float4 nx0 = xp[qn], nx1 = xp[5+qn], nx2 = xp[10+qn], nx3 = xp[15+qn];
        const float xs0[4] = {xc0.x, xc0.y, xc0.z, xc0.w};
        const float xs1[4] = {xc1.x, xc1.y, xc1.z, xc1.w};
        const float xs2[4] = {xc2.x, xc2.y, xc2.z, xc2.w};
        const float xs3[4] = {xc3.x, xc3.y, xc3.z, xc3.w};
        #pragma unroll
        for (int d = 0; d < 4; ++d) {
            const int k = 4*q + d;
            const int kb = k * 5;
            const f2 xk0 = {xs0[d], xs0[d]};
            const f2 xk1 = {xs1[d], xs1[d]};
            const f2 xk2 = {xs2[d], xs2[d]};
            const f2 xk3 = {xs3[d], xs3[d]};
            {
                const v4f w = L4[340 + k];     // Q2T[k]
                const f2 wlo = {w.x, w.y}, whi = {w.z, w.w};
                la2[0][0] = __builtin_elementwise_fma(xk0, wlo, la2[0][0]);
                la2[0][1] = __builtin_elementwise_fma(xk0, whi, la2[0][1]);
                la2[1][0] = __builtin_elementwise_fma(xk1, wlo, la2[1][0]);
                la2[1][1] = __builtin_elementwise_fma(xk1, whi, la2[1][1]);
                la2[2][0] = __builtin_elementwise_fma(xk2, wlo, la2[2][0]);
                la2[2][1] = __builtin_elementwise_fma(xk2, whi, la2[2][1]);
                la2[3][0] = __builtin_elementwise_fma(xk3, wlo, la2[3][0]);
                la2[3][1] = __builtin_elementwise_fma(xk3, whi, la2[3][1]);
            }
            #pragma unroll
            for (int r = 0; r < 5; ++r) {
                const v4f w = L4[kb + r];      // G1[k]
                const f2 wlo = {w.x, w.y}, whi = {w.z, w.w};
                h2[0][2*r+0] = __builtin_elementwise_fma(xk0, wlo, h2[0][2*r+0]);
                h2[0][2*r+1] = __builtin_elementwise_fma(xk0, whi, h2[0][2*r+1]);
                h2[1][2*r+0] = __builtin_elementwise_fma(xk1, wlo, h2[1][2*r+0]);
                h2[1][2*r+1] = __builtin_elementwise_fma(xk1, whi, h2[1][2*r+1]);
                h2[2][2*r+0] = __builtin_elementwise_fma(xk2, wlo, h2[2][2*r+0]);
                h2[2][2*r+1] = __builtin_elementwise_fma(xk2, whi, h2[2][2*r+1]);
                h2[3][2*r+0] = __builtin_elementwise_fma(xk3, wlo, h2[3][2*r+0]);
                h2[3][2*r+1] = __builtin_elementwise_fma(xk3, whi, h2[3][2*r+1]);
            }
            #pragma unroll
            for (int r = 0; r < 5; ++r) {
                const v4f w = L4[200 + kb + r]; // P2[k]
                const f2 wlo = {w.x, w.y}, whi = {w.z, w.w};
                g2[0][2*r+0] = __builtin_elementwise_fma(xk0, wlo, g2[0][2*r+0]);
                g2[0][2*r+1] = __builtin_elementwise_fma(xk0, whi, g2[0][2*r+1]);
                g2[1][2*r+0] = __builtin_elementwise_fma(xk1, wlo, g2[1][2*r+0]);
                g2[1][2*r+1] = __builtin_elementwise_fma(xk1, whi, g2[1][2*r+1]);
                g2[2][2*r+0] = __builtin_elementwise_fma(xk2, wlo, g2[2][2*r+0]);
                g2[2][2*r+1] = __builtin_elementwise_fma(xk2, whi, g2[2][2*r+1]);
                g2[3][2*r+0] = __builtin_elementwise_fma(xk3, wlo, g2[3][2*r+0]);
                g2[3][2*r+1] = __builtin_elementwise_fma(xk3, whi, g2[3][2*r+1]);
            }
        }
        xc0 = nx0; xc1 = nx1; xc2 = nx2; xc3 = nx3;
    }

    // relu h (packed)
    {
        const f2 z2 = {0.f, 0.f};
        #pragma unroll
        for (int t = 0; t < 4; ++t)
            #pragma unroll
            for (int p = 0; p < 10; ++p)
                h2[t][p] = __builtin_elementwise_max(h2[t][p], z2);
    }

    // ---- loop2 (fully unrolled): g += h@P1 ; la += h@Q1T ----
    #pragma unroll
    for (int k = 0; k < 20; ++k) {
        const float hv0 = (k & 1) ? h2[0][k>>1].y : h2[0][k>>1].x;
        const float hv1 = (k & 1) ? h2[1][k>>1].y : h2[1][k>>1].x;
        const float hv2 = (k & 1) ? h2[2][k>>1].y : h2[2][k>>1].x;
        const float hv3 = (k & 1) ? h2[3][k>>1].y : h2[3][k>>1].x;
        const f2 hk0 = {hv0, hv0}, hk1 = {hv1, hv1}, hk2 = {hv2, hv2}, hk3 = {hv3, hv3};
        {
            const v4f w = L4[320 + k];         // Q1T[k]
            const f2 wlo = {w.x, w.y}, whi = {w.z, w.w};
            la2[0][0] = __builtin_elementwise_fma(hk0, wlo, la2[0][0]);
            la2[0][1] = __builtin_elementwise_fma(hk0, whi, la2[0][1]);
            la2[1][0] = __builtin_elementwise_fma(hk1, wlo, la2[1][0]);
            la2[1][1] = __builtin_elementwise_fma(hk1, whi, la2[1][1]);
            la2[2][0] = __builtin_elementwise_fma(hk2, wlo, la2[2][0]);
            la2[2][1] = __builtin_elementwise_fma(hk2, whi, la2[2][1]);
            la2[3][0] = __builtin_elementwise_fma(hk3, wlo, la2[3][0]);
            la2[3][1] = __builtin_elementwise_fma(hk3, whi, la2[3][1]);
        }
        #pragma unroll
        for (int r = 0; r < 5; ++r) {
            const v4f w = L4[100 + k*5 + r];   // P1[k]
            const f2 wlo = {w.x, w.y}, whi = {w.z, w.w};
            g2[0][2*r+0] = __builtin_elementwise_fma(hk0, wlo, g2[0][2*r+0]);
            g2[0][2*r+1] = __builtin_elementwise_fma(hk0, whi, g2[0][2*r+1]);
            g2[1][2*r+0] = __builtin_elementwise_fma(hk1, wlo, g2[1][2*r+0]);
            g2[1][2*r+1] = __builtin_elementwise_fma(hk1, whi, g2[1][2*r+1]);
            g2[2][2*r+0] = __builtin_elementwise_fma(hk2, wlo, g2[2][2*r+0]);
            g2[2][2*r+1] = __builtin_elementwise_fma(hk2, whi, g2[2][2*r+1]);
            g2[3][2*r+0] = __builtin_elementwise_fma(hk3, wlo, g2[3][2*r+0]);
            g2[3][2*r+1] = __builtin_elementwise_fma(hk3, whi, g2[3][2*r+1]);
        }
    }

    // relu g (packed)
    {
        const f2 z2 = {0.f, 0.f};
        #pragma unroll
        for (int t = 0; t < 4; ++t)
            #pragma unroll
            for (int p = 0; p < 10; ++p)
                g2[t][p] = __builtin_elementwise_max(g2[t][p], z2);
    }

    // ---- loop3 (fully unrolled): la += g@M2T (pad col = 0) ----
    #pragma unroll
    for (int k = 0; k < 20; ++k) {
        const float gv0 = (k & 1) ? g2[0][k>>1].y : g2[0][k>>1].x;
        const float gv1 = (k & 1) ? g2[1][k>>1].y : g2[1][k>>1].x;
        const float gv2 = (k & 1) ? g2[2][k>>1].y : g2[2][k>>1].x;
        const float gv3 = (k & 1) ? g2[3][k>>1].y : g2[3][k>>1].x;
        const f2 gk0 = {gv0, gv0}, gk1 = {gv1, gv1}, gk2 = {gv2, gv2}, gk3 = {gv3, gv3};
        const v4f w = L4[300 + k];             // M2T[k]
        const f2 wlo = {w.x, w.y}, whi = {w.z, w.w};
        la2[0][0] = __builtin_elementwise_fma(gk0, wlo, la2[0][0]);
        la2[0][1] = __builtin_elementwise_fma(gk0, whi, la2[0][1]);
        la2[1][0] = __builtin_elementwise_fma(gk1, wlo, la2[1][0]);
        la2[1][1] = __builtin_elementwise_fma(gk1, whi, la2[1][1]);
        la2[2][0] = __builtin_elementwise_fma(gk2, wlo, la2[2][0]);
        la2[2][1] = __builtin_elementwise_fma(gk2, whi, la2[2][1]);
        la2[3][0] = __builtin_elementwise_fma(gk3, wlo, la2[3][0]);
        la2[3][1] = __builtin_elementwise_fma(gk3, whi, la2[3][1]);
    }

    // softmax per token + vectorized store (4 tokens x 3 = 12 floats, 16B-aligned)
    float p[12];
    #pragma unroll
    for (int t = 0; t < 4; ++t) {
        const float l0 = la2[t][0].x, l1 = la2[t][0].y, l2 = la2[t][1].x;
        const float m = fmaxf(fmaxf(l0, l1), l2);
        const float e0 = __expf(l0 - m);
        const float e1 = __expf(l1 - m);
        const float e2 = __expf(l2 - m);
        const float r = 1.f / (e0 + e1 + e2);
        p[3*t+0] = e0 * r; p[3*t+1] = e1 * r; p[3*t+2] = e2 * r;
    }
    float4* op = reinterpret_cast<float4*>(out + (size_t)tid * 12);
    op[0] = make_float4(p[0], p[1], p[2],  p[3]);
    op[1] = make_float4(p[4], p[5], p[6],  p[7]);
    op[2] = make_float4(p[8], p[9], p[10], p[11]);
}

extern "C" void kernel_launch(void* const* d_in, const int* in_sizes, int n_in,
                              void* d_out, int out_size, void* d_ws, size_t ws_size,
                              hipStream_t stream) {
    const float* X    = (const float*)d_in[0];
    // d_in[1]=Wq, d_in[2]=Wk: dead (softmax over singleton axis == 1)
    const float* Wv   = (const float*)d_in[3];
    const float* Wres = (const float*)d_in[4];
    const float* W1   = (const float*)d_in[5];
    const float* b1   = (const float*)d_in[6];
    const float* W2   = (const float*)d_in[7];
    const float* b2   = (const float*)d_in[8];
    const float* W3   = (const float*)d_in[9];
    const float* b3   = (const float*)d_in[10];
    const float* Wc   = (const float*)d_in[11];
    const float* bc   = (const float*)d_in[12];
    float* out = (float*)d_out;
    float* W   = (float*)d_ws;

    const int S = in_sizes[0] / 20;

    prep_kernel<<<1, 256, 0, stream>>>(Wv, Wres, W1, b1, W2, b2, W3, b3, Wc, bc, W);

    const int nquad = S / 4;                   // S = 1048576 divides evenly
    const int block = 256;
    const int grid = (nquad + block - 1) / block;
    fwd_kernel<<<grid, block, 0, stream>>>(X, W, out, nquad);
}